// Round 2
// baseline (409.010 us; speedup 1.0000x reference)
//
#include <hip/hip_runtime.h>
#include <stdint.h>

#define BT      128
#define NPATCH  256
#define DV      1024
#define NB      4
#define NHEADS  4
#define HD      64
#define DB      256
#define NH16    16
#define SCALE   0.125f
#define LNEPS   1e-5f

// ---- ws layout (float element offsets), total ~32.3 MB ----
#define OFF_GWQ    0u          // 16*1024
#define OFF_BWS    16384u      // 16384 u16 bf16 B-frags
#define OFF_S      24576u      // 16
#define OFF_CB     24592u      // 16
#define OFF_PSC    24608u      // 16 nh * 16 ich * 2 partial S/C
#define OFF_DRAW2  25120u      // 2 * 32768 * 16 partial dots
#define OFF_STATS2 1073696u    // 2 * 32768 * 2 partial sum/sq
#define OFF_STATS  1204768u    // 32768 * {mu,rstd}
#define OFF_ATTN   1270304u    // 128*16*256
#define OFF_DIV    1794592u    // 128*6
#define OFF_XBAR   1795360u    // 2 * 128*16*1024
#define OFF_PPOOL  5989664u    // 16 ks * 4 n * 128 bt * 256 c

typedef short bf16x8 __attribute__((ext_vector_type(8)));
typedef float f32x4  __attribute__((ext_vector_type(4)));

__device__ __forceinline__ short f2bf(float f) {   // RNE (used once for B-frags)
    union { float f; unsigned u; } v; v.f = f;
    unsigned u = v.u;
    unsigned r = (u + 0x7fffu + ((u >> 16) & 1u)) >> 16;
    return (short)r;
}

// pack two floats -> two truncated bf16 in one v_perm_b32
__device__ __forceinline__ unsigned pk2(float lo, float hi) {
    union { float f; unsigned u; } a, b; a.f = lo; b.f = hi;
    return __builtin_amdgcn_perm(b.u, a.u, 0x07060302u);
}

// ---- P: partial wq dots, 256 blocks = 16 nh x 16 i-chunks of 64 rows ----
__global__ __launch_bounds__(256) void kP(const float* __restrict__ Wk,
                                          const float* __restrict__ q,
                                          const float* __restrict__ g,
                                          const float* __restrict__ b,
                                          float* __restrict__ ws) {
    const int nh = blockIdx.x >> 4, ich = blockIdx.x & 15;
    const int n = nh >> 2, h = nh & 3;
    __shared__ float qs[64];
    __shared__ float redS[4], redC[4];
    const int t = threadIdx.x;
    if (t < 64) qs[t] = q[nh * 64 + t];
    __syncthreads();
    const int r = t >> 2, qd = t & 3;
    const int i = ich * 64 + r;
    const float* wrow = Wk + ((size_t)n * DV + i) * DB + h * 64 + qd * 16;
    float acc = 0.f;
    #pragma unroll
    for (int d = 0; d < 16; d += 4) {
        float4 w4 = *(const float4*)(wrow + d);
        acc += w4.x * qs[qd * 16 + d]     + w4.y * qs[qd * 16 + d + 1]
             + w4.z * qs[qd * 16 + d + 2] + w4.w * qs[qd * 16 + d + 3];
    }
    acc += __shfl_xor(acc, 1);
    acc += __shfl_xor(acc, 2);             // full 64-d dot in all 4 qd lanes
    float gw = g[i] * acc;
    if (qd == 0) ws[OFF_GWQ + nh * DV + i] = gw;
    float mS = (qd == 0) ? gw : 0.f;
    float mC = (qd == 0) ? b[i] * acc : 0.f;
    #pragma unroll
    for (int dd = 4; dd < 64; dd <<= 1) { mS += __shfl_xor(mS, dd); mC += __shfl_xor(mC, dd); }
    const int wave = t >> 6, lane = t & 63;
    if (lane == 0) { redS[wave] = mS; redC[wave] = mC; }
    __syncthreads();
    if (t == 0) {
        ws[OFF_PSC + (nh * 16 + ich) * 2 + 0] = redS[0] + redS[1] + redS[2] + redS[3];
        ws[OFF_PSC + (nh * 16 + ich) * 2 + 1] = redC[0] + redC[1] + redC[2] + redC[3];
    }
}

// ---- P2: blocks 0..15 pack B-frags; block 16 reduces S/Cb ----
__global__ __launch_bounds__(1024) void kP2(const float* __restrict__ q,
                                            const float* __restrict__ bk,
                                            float* __restrict__ ws) {
    const int blk = blockIdx.x;
    const int t = threadIdx.x;
    if (blk == 16) {
        if (t < 16) {
            const int nh = t, n = nh >> 2, h = nh & 3;
            float S = 0.f, C = 0.f;
            for (int ich = 0; ich < 16; ++ich) {
                S += ws[OFF_PSC + (nh * 16 + ich) * 2 + 0];
                C += ws[OFF_PSC + (nh * 16 + ich) * 2 + 1];
            }
            float bkq = 0.f;
            for (int d = 0; d < 64; ++d) bkq += bk[n * DB + h * 64 + d] * q[nh * 64 + d];
            ws[OFF_S + nh]  = S;
            ws[OFF_CB + nh] = C + bkq;
        }
        return;
    }
    unsigned short* bws = (unsigned short*)(ws + OFF_BWS);
    const float* gwq = ws + OFF_GWQ;
    const int idx = blk * 1024 + t;
    const int j = idx & 7, lane = (idx >> 3) & 63, kt = idx >> 9;
    const int nh = lane & 15;
    const int k = kt * 32 + ((lane >> 4) * 8) + j;
    bws[idx] = (unsigned short)f2bf(gwq[nh * DV + k]);
}

// ---- A: partial raw dots via MFMA + partial LN sums, K-split 2 ----
__global__ __launch_bounds__(256) void kA(const float* __restrict__ x,
                                          float* __restrict__ ws) {
    const int t = threadIdx.x;
    const int wave = t >> 6, lane = t & 63;
    const int task = blockIdx.x * 4 + wave;     // 0..4095
    const int khalf = task & 1, tile = task >> 1;
    const int m = lane & 15, oct = lane >> 4;
    const int row0 = tile * 16;
    const float* xrow = x + (size_t)(row0 + m) * DV + khalf * 512 + oct * 8;
    const bf16x8* bfp = (const bf16x8*)((const unsigned short*)(ws + OFF_BWS)) + khalf * 1024;

    f32x4 acc = {0.f, 0.f, 0.f, 0.f};
    float sum = 0.f, sq = 0.f;
    #pragma unroll 4
    for (int kt = 0; kt < 16; ++kt) {
        float4 a0 = *(const float4*)(xrow + kt * 32);
        float4 a1 = *(const float4*)(xrow + kt * 32 + 4);
        union { bf16x8 v; unsigned w[4]; } af;
        af.w[0] = pk2(a0.x, a0.y); af.w[1] = pk2(a0.z, a0.w);
        af.w[2] = pk2(a1.x, a1.y); af.w[3] = pk2(a1.z, a1.w);
        bf16x8 bfr = bfp[kt * 64 + lane];
        acc = __builtin_amdgcn_mfma_f32_16x16x32_bf16(af.v, bfr, acc, 0, 0, 0);
        sum += a0.x + a0.y + a0.z + a0.w + a1.x + a1.y + a1.z + a1.w;
        sq  += a0.x * a0.x + a0.y * a0.y + a0.z * a0.z + a0.w * a0.w
             + a1.x * a1.x + a1.y * a1.y + a1.z * a1.z + a1.w * a1.w;
    }
    sum += __shfl_xor(sum, 16); sum += __shfl_xor(sum, 32);
    sq  += __shfl_xor(sq, 16);  sq  += __shfl_xor(sq, 32);
    if (lane < 16) {
        ws[OFF_STATS2 + (size_t)khalf * 65536 + (size_t)(row0 + lane) * 2 + 0] = sum;
        ws[OFF_STATS2 + (size_t)khalf * 65536 + (size_t)(row0 + lane) * 2 + 1] = sq;
    }
    #pragma unroll
    for (int r = 0; r < 4; ++r)
        ws[OFF_DRAW2 + (size_t)khalf * 524288 + (size_t)(row0 + oct * 4 + r) * 16 + m] = acc[r];
}

// ---- B: combine partials -> stats + scores -> softmax -> attn + diversity ----
__global__ __launch_bounds__(256) void kB(float* __restrict__ ws) {
    const int bt = blockIdx.x;
    const int t = threadIdx.x;            // patch p in phase 1
    __shared__ __attribute__((aligned(16))) float s_s[NH16 * NPATCH];
    __shared__ __attribute__((aligned(16))) float aavg[NB * NPATCH];
    __shared__ float Ss[NH16], Cbs[NH16];
    if (t < NH16) Ss[t] = ws[OFF_S + t];
    else if (t < 32) Cbs[t - 16] = ws[OFF_CB + (t - 16)];
    const size_t row = (size_t)bt * NPATCH + t;
    const float sum = ws[OFF_STATS2 + row * 2 + 0] + ws[OFF_STATS2 + 65536 + row * 2 + 0];
    const float sq  = ws[OFF_STATS2 + row * 2 + 1] + ws[OFF_STATS2 + 65536 + row * 2 + 1];
    const float mu   = sum * (1.f / 1024.f);
    const float var  = sq * (1.f / 1024.f) - mu * mu;
    const float rstd = rsqrtf(var + LNEPS);
    ws[OFF_STATS + row * 2 + 0] = mu;
    ws[OFF_STATS + row * 2 + 1] = rstd;
    __syncthreads();
    const float* dr0 = ws + OFF_DRAW2 + row * 16;
    const float* dr1 = dr0 + 524288;
    #pragma unroll
    for (int nh = 0; nh < NH16; ++nh) {
        float D = dr0[nh] + dr1[nh];
        s_s[nh * NPATCH + t] = (rstd * (D - mu * Ss[nh]) + Cbs[nh]) * SCALE;
    }
    __syncthreads();
    const int wave = t >> 6, lane = t & 63;
    for (int r = 0; r < 4; ++r) {
        const int nh = wave * 4 + r;
        float4 v = *(float4*)&s_s[nh * NPATCH + lane * 4];
        float mx = fmaxf(fmaxf(v.x, v.y), fmaxf(v.z, v.w));
        for (int d = 1; d < 64; d <<= 1) mx = fmaxf(mx, __shfl_xor(mx, d));
        float e0 = __expf(v.x - mx), e1 = __expf(v.y - mx);
        float e2 = __expf(v.z - mx), e3 = __expf(v.w - mx);
        float s = e0 + e1 + e2 + e3;
        for (int d = 1; d < 64; d <<= 1) s += __shfl_xor(s, d);
        float inv = 1.f / s;
        float4 a; a.x = e0 * inv; a.y = e1 * inv; a.z = e2 * inv; a.w = e3 * inv;
        *(float4*)&s_s[nh * NPATCH + lane * 4] = a;
        *(float4*)(ws + OFF_ATTN + (size_t)(bt * NH16 + nh) * NPATCH + lane * 4) = a;
    }
    __syncthreads();
    #pragma unroll
    for (int n = 0; n < NB; ++n)
        aavg[n * NPATCH + t] = 0.25f * (s_s[(n * 4 + 0) * NPATCH + t] + s_s[(n * 4 + 1) * NPATCH + t]
                                      + s_s[(n * 4 + 2) * NPATCH + t] + s_s[(n * 4 + 3) * NPATCH + t]);
    __syncthreads();
    if (wave == 0) {
        float nrm[NB];
        #pragma unroll
        for (int n = 0; n < NB; ++n) {
            float4 v = *(float4*)&aavg[n * NPATCH + lane * 4];
            float ss = v.x * v.x + v.y * v.y + v.z * v.z + v.w * v.w;
            for (int d = 1; d < 64; d <<= 1) ss += __shfl_xor(ss, d);
            nrm[n] = fmaxf(sqrtf(ss), 1e-8f);
        }
        int pi = 0;
        for (int i = 0; i < NB; ++i)
            for (int j = i + 1; j < NB; ++j) {
                float4 va = *(float4*)&aavg[i * NPATCH + lane * 4];
                float4 vb = *(float4*)&aavg[j * NPATCH + lane * 4];
                float dd = va.x * vb.x + va.y * vb.y + va.z * vb.z + va.w * vb.w;
                for (int d = 1; d < 64; d <<= 1) dd += __shfl_xor(dd, d);
                if (lane == 0) ws[OFF_DIV + bt * 6 + pi] = dd / (nrm[i] * nrm[j]);
                ++pi;
            }
    }
}

// ---- C: xbar half-sums, thread-per-dim ----
__global__ __launch_bounds__(1024) void kC(const float* __restrict__ x,
                                           const float* __restrict__ g,
                                           const float* __restrict__ b,
                                           float* __restrict__ ws) {
    const int bt = blockIdx.x;
    const int half = blockIdx.y;
    const int t = threadIdx.x;             // dim 0..1023
    __shared__ __attribute__((aligned(16))) float att_s[128 * 16];
    __shared__ float st_s[128 * 2];
    for (int idx = t; idx < 2048; idx += 1024) {
        int p = idx >> 4, nh = idx & 15;
        att_s[p * 16 + nh] = ws[OFF_ATTN + (size_t)(bt * NH16 + nh) * NPATCH + half * 128 + p];
    }
    if (t < 256) st_s[t] = ws[OFF_STATS + (size_t)(bt * NPATCH + half * 128) * 2 + t];
    const float gt = g[t], bb = b[t];
    float acc[16];
    #pragma unroll
    for (int i = 0; i < 16; ++i) acc[i] = 0.f;
    __syncthreads();
    const float* xp = x + (size_t)(bt * NPATCH + half * 128) * DV + t;
    #pragma unroll 4
    for (int p = 0; p < 128; ++p) {
        float xv = xp[(size_t)p * DV];
        float y = (xv - st_s[p * 2]) * st_s[p * 2 + 1] * gt + bb;
        float4 a0 = *(const float4*)&att_s[p * 16 + 0];
        float4 a1 = *(const float4*)&att_s[p * 16 + 4];
        float4 a2 = *(const float4*)&att_s[p * 16 + 8];
        float4 a3 = *(const float4*)&att_s[p * 16 + 12];
        acc[0]  += a0.x * y; acc[1]  += a0.y * y; acc[2]  += a0.z * y; acc[3]  += a0.w * y;
        acc[4]  += a1.x * y; acc[5]  += a1.y * y; acc[6]  += a1.z * y; acc[7]  += a1.w * y;
        acc[8]  += a2.x * y; acc[9]  += a2.y * y; acc[10] += a2.z * y; acc[11] += a2.w * y;
        acc[12] += a3.x * y; acc[13] += a3.y * y; acc[14] += a3.z * y; acc[15] += a3.w * y;
    }
    #pragma unroll
    for (int nh = 0; nh < 16; ++nh)
        ws[OFF_XBAR + ((size_t)(half * BT + bt) * 16 + nh) * DV + t] = acc[nh];
}

// ---- D1: partial pooled, register-tiled fp32, K-split 16 ----
// grid 512: bid = ((n*4 + cq)*2 + btg)*16 + ks ; block tile 64c x 64bt x 64i
__global__ __launch_bounds__(256) void kD1(const float* __restrict__ Wv,
                                           float* __restrict__ ws) {
    const int bid = blockIdx.x;
    const int ks = bid & 15, btg = (bid >> 4) & 1, cq = (bid >> 5) & 3, n = bid >> 7;
    const int i0 = ks * 64, bt0 = btg * 64, c0 = cq * 64;
    const int nh = n * 4 + cq;             // c-chunk is head-aligned
    __shared__ __attribute__((aligned(16))) float wv_s[64][64];
    __shared__ __attribute__((aligned(16))) float xs[64][68];
    const int t = threadIdx.x;
    for (int k = 0; k < 16; ++k) {
        const int j = k * 256 + t;
        const int a = j >> 6, d = j & 63;
        wv_s[a][d] = Wv[((size_t)n * DV + i0 + a) * DB + c0 + d];
        // a = bt index, d = i index for xs
        size_t b0 = OFF_XBAR + ((size_t)(bt0 + a) * 16 + nh) * DV + i0 + d;
        xs[d][a] = ws[b0] + ws[b0 + (size_t)BT * 16 * DV];
    }
    __syncthreads();
    const int tc = t & 15, tb = t >> 4;
    float a4[4][4];
    #pragma unroll
    for (int r = 0; r < 4; ++r)
        #pragma unroll
        for (int c = 0; c < 4; ++c) a4[r][c] = 0.f;
    #pragma unroll 4
    for (int i = 0; i < 64; ++i) {
        float4 w4 = *(const float4*)&wv_s[i][tc * 4];
        float4 x4 = *(const float4*)&xs[i][tb * 4];
        a4[0][0] += x4.x * w4.x; a4[0][1] += x4.x * w4.y; a4[0][2] += x4.x * w4.z; a4[0][3] += x4.x * w4.w;
        a4[1][0] += x4.y * w4.x; a4[1][1] += x4.y * w4.y; a4[1][2] += x4.y * w4.z; a4[1][3] += x4.y * w4.w;
        a4[2][0] += x4.z * w4.x; a4[2][1] += x4.z * w4.y; a4[2][2] += x4.z * w4.z; a4[2][3] += x4.z * w4.w;
        a4[3][0] += x4.w * w4.x; a4[3][1] += x4.w * w4.y; a4[3][2] += x4.w * w4.z; a4[3][3] += x4.w * w4.w;
    }
    #pragma unroll
    for (int r = 0; r < 4; ++r) {
        const int bt = bt0 + tb * 4 + r;
        float4 o; o.x = a4[r][0]; o.y = a4[r][1]; o.z = a4[r][2]; o.w = a4[r][3];
        *(float4*)(ws + OFF_PPOOL + ((size_t)(ks * 4 + n) * BT + bt) * DB + c0 + tc * 4) = o;
    }
}

// ---- D2: reduce partials + bv, then out = pooled @ Wo + bo ----
// grid 64: bid = (n*4 + jq)*4 + btg ; block tile 64j x 32bt, K=256 in 4 chunks
__global__ __launch_bounds__(256) void kD2(const float* __restrict__ Wo,
                                           const float* __restrict__ bv,
                                           const float* __restrict__ bo,
                                           const float* __restrict__ ws,
                                           float* __restrict__ out) {
    const int bid = blockIdx.x;
    const int btg = bid & 3, jq = (bid >> 2) & 3, n = bid >> 4;
    const int bt0 = btg * 32, j0 = jq * 64;
    __shared__ __attribute__((aligned(16))) float wo_s[64][64];
    __shared__ float ps[64][37];
    const int t = threadIdx.x;
    const int tj = t & 15, tb = t >> 4;
    float o[2][4];
    #pragma unroll
    for (int r = 0; r < 2; ++r)
        #pragma unroll
        for (int c = 0; c < 4; ++c) o[r][c] = 0.f;
    for (int cc = 0; cc < 4; ++cc) {
        const int cc0 = cc * 64;
        for (int k = 0; k < 16; ++k) {
            const int e = k * 256 + t;
            const int c = e >> 6, j = e & 63;
            wo_s[c][j] = Wo[((size_t)n * DB + cc0 + c) * DB + j0 + j];
        }
        for (int k = 0; k < 8; ++k) {
            const int e = k * 256 + t;
            const int c = e & 63, bt = e >> 6;
            float v = bv[n * DB + cc0 + c];
            const float* pp = ws + OFF_PPOOL + ((size_t)n * BT + bt0 + bt) * DB + cc0 + c;
            #pragma unroll
            for (int s = 0; s < 16; ++s) v += pp[(size_t)s * 4 * BT * DB];
            ps[c][bt] = v;
        }
        __syncthreads();
        #pragma unroll 4
        for (int c = 0; c < 64; ++c) {
            float4 w4 = *(const float4*)&wo_s[c][tj * 4];
            float p0 = ps[c][tb * 2], p1 = ps[c][tb * 2 + 1];
            o[0][0] += p0 * w4.x; o[0][1] += p0 * w4.y; o[0][2] += p0 * w4.z; o[0][3] += p0 * w4.w;
            o[1][0] += p1 * w4.x; o[1][1] += p1 * w4.y; o[1][2] += p1 * w4.z; o[1][3] += p1 * w4.w;
        }
        __syncthreads();
    }
    #pragma unroll
    for (int r = 0; r < 2; ++r) {
        const int bt = bt0 + tb * 2 + r;
        float4 res;
        res.x = o[r][0] + bo[n * DB + j0 + tj * 4 + 0];
        res.y = o[r][1] + bo[n * DB + j0 + tj * 4 + 1];
        res.z = o[r][2] + bo[n * DB + j0 + tj * 4 + 2];
        res.w = o[r][3] + bo[n * DB + j0 + tj * 4 + 3];
        *(float4*)(out + ((size_t)bt * NB + n) * DB + j0 + tj * 4) = res;
    }
}

// ---- E: finalize diversity loss ----
__global__ __launch_bounds__(256) void kE(const float* __restrict__ ws,
                                          float* __restrict__ out) {
    const int t = threadIdx.x;
    float acc = 0.f;
    for (int idx = t; idx < 768; idx += 256) acc += ws[OFF_DIV + idx];
    __shared__ float red[4];
    for (int d = 1; d < 64; d <<= 1) acc += __shfl_xor(acc, d);
    if ((t & 63) == 0) red[t >> 6] = acc;
    __syncthreads();
    if (t == 0) out[131072] = 0.1f * (red[0] + red[1] + red[2] + red[3]) / (6.f * 128.f);
}

extern "C" void kernel_launch(void* const* d_in, const int* in_sizes, int n_in,
                              void* d_out, int out_size, void* d_ws, size_t ws_size,
                              hipStream_t stream) {
    const float* x  = (const float*)d_in[0];
    const float* g  = (const float*)d_in[1];
    const float* b  = (const float*)d_in[2];
    const float* q  = (const float*)d_in[3];
    const float* Wk = (const float*)d_in[4];
    const float* bk = (const float*)d_in[5];
    const float* Wv = (const float*)d_in[6];
    const float* bv = (const float*)d_in[7];
    const float* Wo = (const float*)d_in[8];
    const float* bo = (const float*)d_in[9];
    float* out = (float*)d_out;
    float* ws  = (float*)d_ws;

    hipLaunchKernelGGL(kP,  dim3(256),    dim3(256),  0, stream, Wk, q, g, b, ws);
    hipLaunchKernelGGL(kP2, dim3(17),     dim3(1024), 0, stream, q, bk, ws);
    hipLaunchKernelGGL(kA,  dim3(1024),   dim3(256),  0, stream, x, ws);
    hipLaunchKernelGGL(kB,  dim3(128),    dim3(256),  0, stream, ws);
    hipLaunchKernelGGL(kC,  dim3(128, 2), dim3(1024), 0, stream, x, g, b, ws);
    hipLaunchKernelGGL(kD1, dim3(512),    dim3(256),  0, stream, Wv, ws);
    hipLaunchKernelGGL(kD2, dim3(64),     dim3(256),  0, stream, Wo, bv, bo, ws, out);
    hipLaunchKernelGGL(kE,  dim3(1),      dim3(256),  0, stream, ws, out);
}

// Round 3
// 291.841 us; speedup vs baseline: 1.4015x; 1.4015x over previous
//
#include <hip/hip_runtime.h>
#include <stdint.h>

#define BT      128
#define NPATCH  256
#define DV      1024
#define NB      4
#define DB      256
#define NH16    16
#define SCALE   0.125f
#define LNEPS   1e-5f

// ---- ws layout (float element offsets), total ~24.2 MB ----
#define OFF_GWQ    0u          // 16*1024
#define OFF_BWS    16384u      // 16384 bf16 = 8192 floats
#define OFF_S      24576u      // 16
#define OFF_CB     24592u      // 16
#define OFF_PSC    24608u      // 512
#define OFF_DRAW2  25120u      // 2*32768*16
#define OFF_STATS2 1073696u    // 2*32768*2
#define OFF_W      1204768u    // 128*16*256   (attn * rstd)
#define OFF_CV     1729056u    // 128*16       (sum_p attn*rstd*mu)
#define OFF_DIV    1731104u    // 768
#define OFF_XBAR   1731872u    // 2*128*16*1024 (zraw halves)
#define OFF_POOL   5926176u    // 4*128*256
#define XBAR_HALF  2097152u

typedef short bf16x8 __attribute__((ext_vector_type(8)));
typedef float f32x4  __attribute__((ext_vector_type(4)));

__device__ __forceinline__ short f2bf(float f) {   // RNE
    union { float f; unsigned u; } v; v.f = f;
    unsigned u = v.u;
    unsigned r = (u + 0x7fffu + ((u >> 16) & 1u)) >> 16;
    return (short)r;
}

// pack two floats -> two truncated bf16 in one v_perm_b32
__device__ __forceinline__ unsigned pk2(float lo, float hi) {
    union { float f; unsigned u; } a, b; a.f = lo; b.f = hi;
    return __builtin_amdgcn_perm(b.u, a.u, 0x07060302u);
}

// ---- P: partial wq dots, 256 blocks = 16 nh x 16 i-chunks of 64 rows ----
__global__ __launch_bounds__(256) void kP(const float* __restrict__ Wk,
                                          const float* __restrict__ q,
                                          const float* __restrict__ g,
                                          const float* __restrict__ b,
                                          float* __restrict__ ws) {
    const int nh = blockIdx.x >> 4, ich = blockIdx.x & 15;
    const int n = nh >> 2, h = nh & 3;
    __shared__ float qs[64];
    __shared__ float redS[4], redC[4];
    const int t = threadIdx.x;
    if (t < 64) qs[t] = q[nh * 64 + t];
    __syncthreads();
    const int r = t >> 2, qd = t & 3;
    const int i = ich * 64 + r;
    const float* wrow = Wk + ((size_t)n * DV + i) * DB + h * 64 + qd * 16;
    float acc = 0.f;
    #pragma unroll
    for (int d = 0; d < 16; d += 4) {
        float4 w4 = *(const float4*)(wrow + d);
        acc += w4.x * qs[qd * 16 + d]     + w4.y * qs[qd * 16 + d + 1]
             + w4.z * qs[qd * 16 + d + 2] + w4.w * qs[qd * 16 + d + 3];
    }
    acc += __shfl_xor(acc, 1);
    acc += __shfl_xor(acc, 2);
    float gw = g[i] * acc;
    if (qd == 0) ws[OFF_GWQ + nh * DV + i] = gw;
    float mS = (qd == 0) ? gw : 0.f;
    float mC = (qd == 0) ? b[i] * acc : 0.f;
    #pragma unroll
    for (int dd = 4; dd < 64; dd <<= 1) { mS += __shfl_xor(mS, dd); mC += __shfl_xor(mC, dd); }
    const int wave = t >> 6, lane = t & 63;
    if (lane == 0) { redS[wave] = mS; redC[wave] = mC; }
    __syncthreads();
    if (t == 0) {
        ws[OFF_PSC + (nh * 16 + ich) * 2 + 0] = redS[0] + redS[1] + redS[2] + redS[3];
        ws[OFF_PSC + (nh * 16 + ich) * 2 + 1] = redC[0] + redC[1] + redC[2] + redC[3];
    }
}

// ---- P2: blocks 0..15 pack B-frags; block 16 reduces S/Cb ----
__global__ __launch_bounds__(1024) void kP2(const float* __restrict__ q,
                                            const float* __restrict__ bk,
                                            float* __restrict__ ws) {
    const int blk = blockIdx.x;
    const int t = threadIdx.x;
    if (blk == 16) {
        if (t < 16) {
            const int nh = t, n = nh >> 2, h = nh & 3;
            float S = 0.f, C = 0.f;
            for (int ich = 0; ich < 16; ++ich) {
                S += ws[OFF_PSC + (nh * 16 + ich) * 2 + 0];
                C += ws[OFF_PSC + (nh * 16 + ich) * 2 + 1];
            }
            float bkq = 0.f;
            for (int d = 0; d < 64; ++d) bkq += bk[n * DB + h * 64 + d] * q[nh * 64 + d];
            ws[OFF_S + nh]  = S;
            ws[OFF_CB + nh] = C + bkq;
        }
        return;
    }
    unsigned short* bws = (unsigned short*)(ws + OFF_BWS);
    const float* gwq = ws + OFF_GWQ;
    const int idx = blk * 1024 + t;
    const int j = idx & 7, lane = (idx >> 3) & 63, kt = idx >> 9;
    const int nh = lane & 15;
    const int k = kt * 32 + ((lane >> 4) * 8) + j;
    bws[idx] = (unsigned short)f2bf(gwq[nh * DV + k]);
}

// ---- A: partial raw dots via MFMA + partial LN sums, K-split 2 ----
__global__ __launch_bounds__(256) void kA(const float* __restrict__ x,
                                          float* __restrict__ ws) {
    const int t = threadIdx.x;
    const int wave = t >> 6, lane = t & 63;
    const int task = blockIdx.x * 4 + wave;
    const int khalf = task & 1, tile = task >> 1;
    const int m = lane & 15, oct = lane >> 4;
    const int row0 = tile * 16;
    const float* xrow = x + (size_t)(row0 + m) * DV + khalf * 512 + oct * 8;
    const bf16x8* bfp = (const bf16x8*)((const unsigned short*)(ws + OFF_BWS)) + khalf * 1024;

    f32x4 acc = {0.f, 0.f, 0.f, 0.f};
    float sum = 0.f, sq = 0.f;
    #pragma unroll 4
    for (int kt = 0; kt < 16; ++kt) {
        float4 a0 = *(const float4*)(xrow + kt * 32);
        float4 a1 = *(const float4*)(xrow + kt * 32 + 4);
        union { bf16x8 v; unsigned w[4]; } af;
        af.w[0] = pk2(a0.x, a0.y); af.w[1] = pk2(a0.z, a0.w);
        af.w[2] = pk2(a1.x, a1.y); af.w[3] = pk2(a1.z, a1.w);
        bf16x8 bfr = bfp[kt * 64 + lane];
        acc = __builtin_amdgcn_mfma_f32_16x16x32_bf16(af.v, bfr, acc, 0, 0, 0);
        sum += a0.x + a0.y + a0.z + a0.w + a1.x + a1.y + a1.z + a1.w;
        sq  += a0.x * a0.x + a0.y * a0.y + a0.z * a0.z + a0.w * a0.w
             + a1.x * a1.x + a1.y * a1.y + a1.z * a1.z + a1.w * a1.w;
    }
    sum += __shfl_xor(sum, 16); sum += __shfl_xor(sum, 32);
    sq  += __shfl_xor(sq, 16);  sq  += __shfl_xor(sq, 32);
    if (lane < 16) {
        ws[OFF_STATS2 + (size_t)khalf * 65536 + (size_t)(row0 + lane) * 2 + 0] = sum;
        ws[OFF_STATS2 + (size_t)khalf * 65536 + (size_t)(row0 + lane) * 2 + 1] = sq;
    }
    #pragma unroll
    for (int r = 0; r < 4; ++r)
        ws[OFF_DRAW2 + (size_t)khalf * 524288 + (size_t)(row0 + oct * 4 + r) * 16 + m] = acc[r];
}

// ---- B: stats + scores -> softmax -> W=attn*rstd, CV, diversity ----
__global__ __launch_bounds__(256) void kB(float* __restrict__ ws) {
    const int bt = blockIdx.x;
    const int t = threadIdx.x;            // patch p
    __shared__ __attribute__((aligned(16))) float s_s[NH16 * NPATCH];
    __shared__ __attribute__((aligned(16))) float aavg[NB * NPATCH];
    __shared__ __attribute__((aligned(16))) float rstd_s[NPATCH];
    __shared__ __attribute__((aligned(16))) float mrs[NPATCH];
    __shared__ float Ss[NH16], Cbs[NH16];
    if (t < NH16) Ss[t] = ws[OFF_S + t];
    else if (t < 32) Cbs[t - 16] = ws[OFF_CB + (t - 16)];
    const size_t row = (size_t)bt * NPATCH + t;
    const float sum = ws[OFF_STATS2 + row * 2 + 0] + ws[OFF_STATS2 + 65536 + row * 2 + 0];
    const float sq  = ws[OFF_STATS2 + row * 2 + 1] + ws[OFF_STATS2 + 65536 + row * 2 + 1];
    const float mu   = sum * (1.f / 1024.f);
    const float var  = sq * (1.f / 1024.f) - mu * mu;
    const float rstd = rsqrtf(var + LNEPS);
    rstd_s[t] = rstd;
    mrs[t] = mu * rstd;
    __syncthreads();
    const float* dr0 = ws + OFF_DRAW2 + row * 16;
    const float* dr1 = dr0 + 524288;
    #pragma unroll
    for (int nh = 0; nh < NH16; ++nh) {
        float D = dr0[nh] + dr1[nh];
        s_s[nh * NPATCH + t] = (rstd * (D - mu * Ss[nh]) + Cbs[nh]) * SCALE;
    }
    __syncthreads();
    const int wave = t >> 6, lane = t & 63;
    for (int r = 0; r < 4; ++r) {
        const int nh = wave * 4 + r;
        float4 v = *(float4*)&s_s[nh * NPATCH + lane * 4];
        float mx = fmaxf(fmaxf(v.x, v.y), fmaxf(v.z, v.w));
        for (int d = 1; d < 64; d <<= 1) mx = fmaxf(mx, __shfl_xor(mx, d));
        float e0 = __expf(v.x - mx), e1 = __expf(v.y - mx);
        float e2 = __expf(v.z - mx), e3 = __expf(v.w - mx);
        float s = e0 + e1 + e2 + e3;
        for (int d = 1; d < 64; d <<= 1) s += __shfl_xor(s, d);
        float inv = 1.f / s;
        float4 a; a.x = e0 * inv; a.y = e1 * inv; a.z = e2 * inv; a.w = e3 * inv;
        *(float4*)&s_s[nh * NPATCH + lane * 4] = a;
        float4 r4 = *(float4*)&rstd_s[lane * 4];
        float4 wv; wv.x = a.x * r4.x; wv.y = a.y * r4.y; wv.z = a.z * r4.z; wv.w = a.w * r4.w;
        *(float4*)(ws + OFF_W + (size_t)(bt * NH16 + nh) * NPATCH + lane * 4) = wv;
    }
    __syncthreads();
    // CV[bt,nh] = sum_p attn*rstd*mu
    for (int r = 0; r < 4; ++r) {
        const int nh = wave * 4 + r;
        float4 a4 = *(float4*)&s_s[nh * NPATCH + lane * 4];
        float4 m4 = *(float4*)&mrs[lane * 4];
        float dd = a4.x * m4.x + a4.y * m4.y + a4.z * m4.z + a4.w * m4.w;
        for (int d = 1; d < 64; d <<= 1) dd += __shfl_xor(dd, d);
        if (lane == 0) ws[OFF_CV + bt * NH16 + nh] = dd;
    }
    #pragma unroll
    for (int n = 0; n < NB; ++n)
        aavg[n * NPATCH + t] = 0.25f * (s_s[(n * 4 + 0) * NPATCH + t] + s_s[(n * 4 + 1) * NPATCH + t]
                                      + s_s[(n * 4 + 2) * NPATCH + t] + s_s[(n * 4 + 3) * NPATCH + t]);
    __syncthreads();
    if (wave == 0) {
        float nrm[NB];
        #pragma unroll
        for (int n = 0; n < NB; ++n) {
            float4 v = *(float4*)&aavg[n * NPATCH + lane * 4];
            float ss = v.x * v.x + v.y * v.y + v.z * v.z + v.w * v.w;
            for (int d = 1; d < 64; d <<= 1) ss += __shfl_xor(ss, d);
            nrm[n] = fmaxf(sqrtf(ss), 1e-8f);
        }
        int pi = 0;
        for (int i = 0; i < NB; ++i)
            for (int j = i + 1; j < NB; ++j) {
                float4 va = *(float4*)&aavg[i * NPATCH + lane * 4];
                float4 vb = *(float4*)&aavg[j * NPATCH + lane * 4];
                float dd = va.x * vb.x + va.y * vb.y + va.z * vb.z + va.w * vb.w;
                for (int d = 1; d < 64; d <<= 1) dd += __shfl_xor(dd, d);
                if (lane == 0) ws[OFF_DIV + bt * 6 + pi] = dd / (nrm[i] * nrm[j]);
                ++pi;
            }
    }
}

// ---- C: zraw[half,bt,nh,:] = sum_p w[nh,p] * x[bt,p,:]  (raw pooling) ----
__global__ __launch_bounds__(512) void kC(const float* __restrict__ x,
                                          float* __restrict__ ws) {
    const int bt = blockIdx.x;
    const int half = blockIdx.y;
    const int t = threadIdx.x;             // 0..511, dims d0=t*2
    __shared__ __attribute__((aligned(16))) float w_s[128 * 16];
    for (int idx = t; idx < 2048; idx += 512) {
        int p = idx >> 4, nh = idx & 15;
        w_s[idx] = ws[OFF_W + (size_t)(bt * NH16 + nh) * NPATCH + half * 128 + p];
    }
    float2 acc[16];
    #pragma unroll
    for (int i = 0; i < 16; ++i) { acc[i].x = 0.f; acc[i].y = 0.f; }
    __syncthreads();
    const float* xp = x + (size_t)(bt * NPATCH + half * 128) * DV + t * 2;
    #pragma unroll 8
    for (int p = 0; p < 128; ++p) {
        float2 xv = *(const float2*)(xp + (size_t)p * DV);
        float4 a0 = *(const float4*)&w_s[p * 16 + 0];
        float4 a1 = *(const float4*)&w_s[p * 16 + 4];
        float4 a2 = *(const float4*)&w_s[p * 16 + 8];
        float4 a3 = *(const float4*)&w_s[p * 16 + 12];
        acc[0].x  += a0.x * xv.x; acc[0].y  += a0.x * xv.y;
        acc[1].x  += a0.y * xv.x; acc[1].y  += a0.y * xv.y;
        acc[2].x  += a0.z * xv.x; acc[2].y  += a0.z * xv.y;
        acc[3].x  += a0.w * xv.x; acc[3].y  += a0.w * xv.y;
        acc[4].x  += a1.x * xv.x; acc[4].y  += a1.x * xv.y;
        acc[5].x  += a1.y * xv.x; acc[5].y  += a1.y * xv.y;
        acc[6].x  += a1.z * xv.x; acc[6].y  += a1.z * xv.y;
        acc[7].x  += a1.w * xv.x; acc[7].y  += a1.w * xv.y;
        acc[8].x  += a2.x * xv.x; acc[8].y  += a2.x * xv.y;
        acc[9].x  += a2.y * xv.x; acc[9].y  += a2.y * xv.y;
        acc[10].x += a2.z * xv.x; acc[10].y += a2.z * xv.y;
        acc[11].x += a2.w * xv.x; acc[11].y += a2.w * xv.y;
        acc[12].x += a3.x * xv.x; acc[12].y += a3.x * xv.y;
        acc[13].x += a3.y * xv.x; acc[13].y += a3.y * xv.y;
        acc[14].x += a3.z * xv.x; acc[14].y += a3.z * xv.y;
        acc[15].x += a3.w * xv.x; acc[15].y += a3.w * xv.y;
    }
    #pragma unroll
    for (int nh = 0; nh < 16; ++nh)
        *(float2*)(ws + OFF_XBAR + (size_t)half * XBAR_HALF
                   + ((size_t)bt * NH16 + nh) * DV + t * 2) = acc[nh];
}

// ---- D1: pooled = (zraw - CV)*g@Wv folded; grid 256 = 16 nh x 16 btg ----
__global__ __launch_bounds__(256) void kD1(const float* __restrict__ Wv,
                                           const float* __restrict__ g,
                                           const float* __restrict__ b,
                                           const float* __restrict__ bv,
                                           float* __restrict__ ws) {
    const int nh = blockIdx.x & 15, btg = blockIdx.x >> 4;
    const int n = nh >> 2, h = nh & 3;
    const int bt0 = btg * 8, cb = h * 64;
    __shared__ __attribute__((aligned(16))) float xs[8][1024];
    __shared__ __attribute__((aligned(16))) float gs[1024], bs[1024];
    __shared__ float red[4][64][10];
    const int t = threadIdx.x;
    for (int e = t; e < 2048; e += 256) {
        const int bt = e >> 8, i4 = e & 255;
        const size_t b0 = OFF_XBAR + ((size_t)(bt0 + bt) * NH16 + nh) * DV + i4 * 4;
        float4 v0 = *(const float4*)(ws + b0);
        float4 v1 = *(const float4*)(ws + b0 + XBAR_HALF);
        float4 s; s.x = v0.x + v1.x; s.y = v0.y + v1.y; s.z = v0.z + v1.z; s.w = v0.w + v1.w;
        *(float4*)&xs[bt][i4 * 4] = s;
    }
    for (int e = t; e < 1024; e += 256) { gs[e] = g[e]; bs[e] = b[e]; }
    __syncthreads();
    const int c = t & 63, sub = t >> 6;
    float acc[8];
    #pragma unroll
    for (int l = 0; l < 8; ++l) acc[l] = 0.f;
    float gv = 0.f, bvv = 0.f;
    const float* wvp = Wv + ((size_t)n * DV + sub * 256) * DB + cb + c;
    const int ib0 = sub * 256;
    #pragma unroll 2
    for (int gidx = 0; gidx < 64; ++gidx) {
        const int ib = ib0 + gidx * 4;
        float w0 = wvp[(size_t)(gidx * 4 + 0) * DB];
        float w1 = wvp[(size_t)(gidx * 4 + 1) * DB];
        float w2 = wvp[(size_t)(gidx * 4 + 2) * DB];
        float w3 = wvp[(size_t)(gidx * 4 + 3) * DB];
        float4 g4 = *(const float4*)&gs[ib];
        float4 b4 = *(const float4*)&bs[ib];
        float q0 = g4.x * w0, q1 = g4.y * w1, q2 = g4.z * w2, q3 = g4.w * w3;
        gv  += q0 + q1 + q2 + q3;
        bvv += b4.x * w0 + b4.y * w1 + b4.z * w2 + b4.w * w3;
        #pragma unroll
        for (int l = 0; l < 8; ++l) {
            float4 xr = *(const float4*)&xs[l][ib];
            acc[l] += xr.x * q0 + xr.y * q1 + xr.z * q2 + xr.w * q3;
        }
    }
    #pragma unroll
    for (int l = 0; l < 8; ++l) red[sub][c][l] = acc[l];
    red[sub][c][8] = gv; red[sub][c][9] = bvv;
    __syncthreads();
    const int c2 = t & 63, l0 = t >> 6;
    float gvS = red[0][c2][8] + red[1][c2][8] + red[2][c2][8] + red[3][c2][8];
    float bvS = red[0][c2][9] + red[1][c2][9] + red[2][c2][9] + red[3][c2][9];
    float base = bv[n * DB + cb + c2] + bvS;
    #pragma unroll
    for (int li = 0; li < 2; ++li) {
        const int l = l0 + li * 4;
        float p = red[0][c2][l] + red[1][c2][l] + red[2][c2][l] + red[3][c2][l];
        float C = ws[OFF_CV + (bt0 + l) * NH16 + nh];
        ws[OFF_POOL + ((size_t)n * BT + bt0 + l) * DB + cb + c2] = p - C * gvS + base;
    }
}

// ---- D2: out = pooled @ Wo + bo ; grid 256 = 4n x 4jq x 16 btg ----
__global__ __launch_bounds__(256) void kD2(const float* __restrict__ Wo,
                                           const float* __restrict__ bo,
                                           const float* __restrict__ ws,
                                           float* __restrict__ out) {
    const int btg = blockIdx.x & 15, jq = (blockIdx.x >> 4) & 3, n = blockIdx.x >> 6;
    const int bt0 = btg * 8, j0 = jq * 64;
    __shared__ __attribute__((aligned(16))) float ps[8][256];
    __shared__ float red[4][64][8];
    const int t = threadIdx.x;
    for (int e = t; e < 512; e += 256) {
        const int bt = e >> 6, c4 = e & 63;
        *(float4*)&ps[bt][c4 * 4] =
            *(const float4*)(ws + OFF_POOL + ((size_t)n * BT + bt0 + bt) * DB + c4 * 4);
    }
    __syncthreads();
    const int j = t & 63, sub = t >> 6;
    float acc[8];
    #pragma unroll
    for (int l = 0; l < 8; ++l) acc[l] = 0.f;
    const float* wop = Wo + ((size_t)n * DB + sub * 64) * DB + j0 + j;
    const int cb0 = sub * 64;
    #pragma unroll 2
    for (int gidx = 0; gidx < 16; ++gidx) {
        const int cb = cb0 + gidx * 4;
        float w0 = wop[(size_t)(gidx * 4 + 0) * DB];
        float w1 = wop[(size_t)(gidx * 4 + 1) * DB];
        float w2 = wop[(size_t)(gidx * 4 + 2) * DB];
        float w3 = wop[(size_t)(gidx * 4 + 3) * DB];
        #pragma unroll
        for (int l = 0; l < 8; ++l) {
            float4 pr = *(const float4*)&ps[l][cb];
            acc[l] += pr.x * w0 + pr.y * w1 + pr.z * w2 + pr.w * w3;
        }
    }
    #pragma unroll
    for (int l = 0; l < 8; ++l) red[sub][j][l] = acc[l];
    __syncthreads();
    const int j2 = t & 63, l0 = t >> 6;
    float bov = bo[n * DB + j0 + j2];
    #pragma unroll
    for (int li = 0; li < 2; ++li) {
        const int l = l0 + li * 4;
        float o = red[0][j2][l] + red[1][j2][l] + red[2][j2][l] + red[3][j2][l] + bov;
        out[((size_t)(bt0 + l) * NB + n) * DB + j0 + j2] = o;
    }
}

// ---- E: finalize diversity loss ----
__global__ __launch_bounds__(256) void kE(const float* __restrict__ ws,
                                          float* __restrict__ out) {
    const int t = threadIdx.x;
    float acc = 0.f;
    for (int idx = t; idx < 768; idx += 256) acc += ws[OFF_DIV + idx];
    __shared__ float red[4];
    for (int d = 1; d < 64; d <<= 1) acc += __shfl_xor(acc, d);
    if ((t & 63) == 0) red[t >> 6] = acc;
    __syncthreads();
    if (t == 0) out[131072] = 0.1f * (red[0] + red[1] + red[2] + red[3]) / (6.f * 128.f);
}

extern "C" void kernel_launch(void* const* d_in, const int* in_sizes, int n_in,
                              void* d_out, int out_size, void* d_ws, size_t ws_size,
                              hipStream_t stream) {
    const float* x  = (const float*)d_in[0];
    const float* g  = (const float*)d_in[1];
    const float* b  = (const float*)d_in[2];
    const float* q  = (const float*)d_in[3];
    const float* Wk = (const float*)d_in[4];
    const float* bk = (const float*)d_in[5];
    const float* Wv = (const float*)d_in[6];
    const float* bv = (const float*)d_in[7];
    const float* Wo = (const float*)d_in[8];
    const float* bo = (const float*)d_in[9];
    float* out = (float*)d_out;
    float* ws  = (float*)d_ws;

    hipLaunchKernelGGL(kP,  dim3(256),    dim3(256),  0, stream, Wk, q, g, b, ws);
    hipLaunchKernelGGL(kP2, dim3(17),     dim3(1024), 0, stream, q, bk, ws);
    hipLaunchKernelGGL(kA,  dim3(1024),   dim3(256),  0, stream, x, ws);
    hipLaunchKernelGGL(kB,  dim3(128),    dim3(256),  0, stream, ws);
    hipLaunchKernelGGL(kC,  dim3(128, 2), dim3(512),  0, stream, x, ws);
    hipLaunchKernelGGL(kD1, dim3(256),    dim3(256),  0, stream, Wv, g, b, bv, ws);
    hipLaunchKernelGGL(kD2, dim3(256),    dim3(256),  0, stream, Wo, bo, ws, out);
    hipLaunchKernelGGL(kE,  dim3(1),      dim3(256),  0, stream, ws, out);
}